// Round 6
// baseline (342.982 us; speedup 1.0000x reference)
//
#include <hip/hip_runtime.h>

typedef unsigned short u16;
typedef __attribute__((ext_vector_type(8))) __bf16 bf16x8;
typedef __attribute__((ext_vector_type(4))) float f32x4;

#define D_MODEL 2048
#define SEQ 2048
#define NHEAD 16
#define HDIM 128

#define AS1 __attribute__((address_space(1)))
#define AS3 __attribute__((address_space(3)))
#define GL2LDS(g, l) __builtin_amdgcn_global_load_lds((AS1 const void*)(g), (AS3 void*)(l), 16, 0, 0)

__device__ __forceinline__ u16 f2bf(float f) {
  unsigned u = __float_as_uint(f);
  u += 0x7fff + ((u >> 16) & 1);   // RNE
  return (u16)(u >> 16);
}
__device__ __forceinline__ float bf2f(u16 h) {
  return __uint_as_float(((unsigned)h) << 16);
}
__device__ __forceinline__ float fexp2(float x) {
#if __has_builtin(__builtin_amdgcn_exp2f)
  return __builtin_amdgcn_exp2f(x);
#else
  return __expf(x * 0.69314718055994531f);
#endif
}

// ---------------- fused fp32 -> bf16 casts (7 tensors, one launch) ----------------
__global__ __launch_bounds__(256) void k_cast7(const float* i0, const float* i1, const float* i2,
                                               const float* i3, const float* i4, const float* i5,
                                               const float* i6,
                                               u16* o0, u16* o1, u16* o2, u16* o3, u16* o4,
                                               u16* o5, u16* o6) {
  const float* in; u16* out;
  switch (blockIdx.y) {
    case 0: in = i0; out = o0; break;
    case 1: in = i1; out = o1; break;
    case 2: in = i2; out = o2; break;
    case 3: in = i3; out = o3; break;
    case 4: in = i4; out = o4; break;
    case 5: in = i5; out = o5; break;
    default: in = i6; out = o6; break;
  }
  const int i = blockIdx.x * blockDim.x + threadIdx.x;
  const float4 v = reinterpret_cast<const float4*>(in)[i];
  ushort4 o;
  o.x = f2bf(v.x); o.y = f2bf(v.y); o.z = f2bf(v.z); o.w = f2bf(v.w);
  reinterpret_cast<ushort4*>(out)[i] = o;
}

// ---------------- GEMM staging: 128x64 tile, rows of 8 chunks, chunk ^= (row&7) swizzle ----------------
__device__ __forceinline__ void stage128(const u16* __restrict__ P, u16* dst, int row0, int kt,
                                         int t, int w) {
#pragma unroll
  for (int c = 0; c < 4; ++c) {
    const int r = (c * 2048 + t * 8) >> 6;            // tile row 0..127
    const int ch = ((t & 7) ^ (r & 7)) * 8;           // swizzled k-chunk
    GL2LDS(P + (size_t)(row0 + r) * D_MODEL + kt + ch, dst + c * 2048 + w * 512);
  }
}
__device__ __forceinline__ void stage64(const u16* __restrict__ P, u16* dst, int row0, int kt,
                                        int t, int w) {
#pragma unroll
  for (int c = 0; c < 2; ++c) {
    const int r = (c * 2048 + t * 8) >> 6;            // tile row 0..63
    const int ch = ((t & 7) ^ (r & 7)) * 8;
    GL2LDS(P + (size_t)(row0 + r) * D_MODEL + kt + ch, dst + c * 2048 + w * 512);
  }
}

// ---------------- NT GEMM: C[m,n] = sum_k A[m,k]*B[n,k], 128x128 tile, dbuf prefetch ----------------
__device__ __forceinline__ void gemm_nt_body(const u16* __restrict__ A, const u16* __restrict__ B,
                                             void* __restrict__ C, u16* As0, u16* As1,
                                             u16* Bs0, u16* Bs1, int outmode) {
  const int tn = blockIdx.x, tm = blockIdx.y;
  const int t = threadIdx.x;
  const int lane = t & 63, w = t >> 6;
  const int wr = w >> 1, wc = w & 1;
  const int lrow = lane & 15, g = lane >> 4;
  f32x4 acc[4][4] = {};

  stage128(A, As0, tm * 128, 0, t, w);
  stage128(B, Bs0, tn * 128, 0, t, w);
  __syncthreads();

  u16 *Ar = As0, *Br = Bs0, *Aw = As1, *Bw = Bs1;
#pragma unroll 1
  for (int kt = 0; kt < D_MODEL; kt += 64) {
    if (kt + 64 < D_MODEL) {           // issue next-tile loads BEFORE compute
      stage128(A, Aw, tm * 128, kt + 64, t, w);
      stage128(B, Bw, tn * 128, kt + 64, t, w);
    }
#pragma unroll
    for (int kk = 0; kk < 2; ++kk) {
      bf16x8 af[4], bfr[4];
#pragma unroll
      for (int i = 0; i < 4; ++i) {
        const int sw = (((kk << 2) + g) ^ (lrow & 7)) * 8;
        af[i]  = *(const bf16x8*)(Ar + (wr * 64 + i * 16 + lrow) * 64 + sw);
        bfr[i] = *(const bf16x8*)(Br + (wc * 64 + i * 16 + lrow) * 64 + sw);
      }
#pragma unroll
      for (int i = 0; i < 4; ++i)
#pragma unroll
        for (int j = 0; j < 4; ++j)
          acc[i][j] = __builtin_amdgcn_mfma_f32_16x16x32_bf16(af[i], bfr[j], acc[i][j], 0, 0, 0);
    }
    __syncthreads();
    u16* tp;
    tp = Ar; Ar = Aw; Aw = tp;
    tp = Br; Br = Bw; Bw = tp;
  }

  // C layout (measured m89): col = lane&15, row = (lane>>4)*4 + reg
  const int crow0 = tm * 128 + wr * 64 + (lane >> 4) * 4;
  const int ccol0 = tn * 128 + wc * 64 + lrow;
  if (outmode == 2) {
#pragma unroll
    for (int i = 0; i < 4; ++i)
#pragma unroll
      for (int j = 0; j < 4; ++j) {
        ushort4 o;
        o.x = f2bf(acc[i][j][0]); o.y = f2bf(acc[i][j][1]);
        o.z = f2bf(acc[i][j][2]); o.w = f2bf(acc[i][j][3]);
        *(ushort4*)((u16*)C + (size_t)(ccol0 + j * 16) * D_MODEL + crow0 + i * 16) = o;
      }
  } else {
#pragma unroll
    for (int i = 0; i < 4; ++i)
#pragma unroll
      for (int j = 0; j < 4; ++j)
#pragma unroll
        for (int r = 0; r < 4; ++r)
          ((u16*)C)[(size_t)(crow0 + i * 16 + r) * D_MODEL + ccol0 + j * 16] = f2bf(acc[i][j][r]);
  }
}

__global__ __launch_bounds__(256, 2) void k_gemm_qkv(const u16* Xq, const u16* Xk, const u16* Xv,
                                                     const u16* Wq, const u16* Wk, const u16* Wv,
                                                     u16* Q, u16* K, u16* VT) {
  __shared__ u16 As[2][128 * 64], Bs[2][128 * 64];
  const int z = blockIdx.z;
  const u16* A = (z == 0) ? Xq : (z == 1) ? Xk : Xv;
  const u16* B = (z == 0) ? Wq : (z == 1) ? Wk : Wv;
  u16* C = (z == 0) ? Q : (z == 1) ? K : VT;
  gemm_nt_body(A, B, C, As[0], As[1], Bs[0], Bs[1], (z == 2) ? 2 : 0);
}

// ---------------- out-proj GEMM: 128x64 tiles -> 512 blocks, dbuf prefetch ----------------
__global__ __launch_bounds__(256, 2) void k_gemm_out(const u16* __restrict__ A, const u16* __restrict__ B,
                                                     float* __restrict__ C) {
  __shared__ u16 As[2][128 * 64], Bs[2][64 * 64];
  const int tn = blockIdx.x, tm = blockIdx.y;
  const int t = threadIdx.x;
  const int lane = t & 63, w = t >> 6;
  const int wr = w >> 1, wc = w & 1;
  const int lrow = lane & 15, g = lane >> 4;
  f32x4 acc[4][2] = {};

  stage128(A, As[0], tm * 128, 0, t, w);
  stage64(B, Bs[0], tn * 64, 0, t, w);
  __syncthreads();

  u16 *Ar = As[0], *Br = Bs[0], *Aw = As[1], *Bw = Bs[1];
#pragma unroll 1
  for (int kt = 0; kt < D_MODEL; kt += 64) {
    if (kt + 64 < D_MODEL) {
      stage128(A, Aw, tm * 128, kt + 64, t, w);
      stage64(B, Bw, tn * 64, kt + 64, t, w);
    }
#pragma unroll
    for (int kk = 0; kk < 2; ++kk) {
      bf16x8 af[4], bfr[2];
#pragma unroll
      for (int i = 0; i < 4; ++i) {
        const int sw = (((kk << 2) + g) ^ (lrow & 7)) * 8;
        af[i] = *(const bf16x8*)(Ar + (wr * 64 + i * 16 + lrow) * 64 + sw);
        if (i < 2) bfr[i] = *(const bf16x8*)(Br + (wc * 32 + i * 16 + lrow) * 64 + sw);
      }
#pragma unroll
      for (int i = 0; i < 4; ++i)
#pragma unroll
        for (int j = 0; j < 2; ++j)
          acc[i][j] = __builtin_amdgcn_mfma_f32_16x16x32_bf16(af[i], bfr[j], acc[i][j], 0, 0, 0);
    }
    __syncthreads();
    u16* tp;
    tp = Ar; Ar = Aw; Aw = tp;
    tp = Br; Br = Bw; Bw = tp;
  }
  const int crow0 = tm * 128 + wr * 64 + (lane >> 4) * 4;
  const int ccol0 = tn * 64 + wc * 32 + lrow;
#pragma unroll
  for (int i = 0; i < 4; ++i)
#pragma unroll
    for (int j = 0; j < 2; ++j)
#pragma unroll
      for (int r = 0; r < 4; ++r)
        C[(size_t)(crow0 + i * 16 + r) * D_MODEL + ccol0 + j * 16] = acc[i][j][r];
}

// ---------------- RoPE (rotate_half); Q gets log2(e)/sqrt(hd) for exp2-domain softmax ----------------
__global__ __launch_bounds__(256) void k_rope(u16* Q, u16* K) {
  const int idx = blockIdx.x * blockDim.x + threadIdx.x; // 0 .. SEQ*NHEAD*64-1
  u16* X = blockIdx.y ? K : Q;
  const float scale = blockIdx.y ? 1.0f : (1.4426950408889634f * 0.08838834764831845f);
  const int s = idx >> 10;
  const int h = (idx >> 6) & 15;
  const int j = idx & 63;
  const float freq = __expf((float)j * -0.14391156831212787f); // -ln(10000)/64
  float sn, cs;
  sincosf((float)s * freq, &sn, &cs);
  const size_t base = (size_t)s * D_MODEL + h * HDIM + j;
  const float x1 = bf2f(X[base]), x2 = bf2f(X[base + 64]);
  X[base]      = f2bf((x1 * cs - x2 * sn) * scale);
  X[base + 64] = f2bf((x2 * cs + x1 * sn) * scale);
}

// ---------------- causal flash attention: balanced pairing + split-KV + dbuf staging ----------------
// 256 blocks x 256 thr, 1 block/CU. Block (h = bx&15, pj = bx>>4) processes q-tiles pj then 31-pj
// -> exactly 33 kv-steps per block (perfect balance, robust to dispatch order).
// 4 waves = 2 M-halves x 2 KV-parities; K/V super-step staging double-buffered (prefetch before compute).
// LDS: Kb 64K + Vb 64K + Pl 16K = 144 KB (1 block/CU by construction).
__global__ __launch_bounds__(256) void k_attn(const u16* __restrict__ Q, const u16* __restrict__ K,
                                              const u16* __restrict__ VT, u16* __restrict__ O) {
  __shared__ u16 Kb[2][2][64 * 128];  // [buf][parity][row][chunk ^ (row&15)]
  __shared__ u16 Vb[2][2][128 * 64];  // [buf][parity][row][chunk ^ (row&7)]
  __shared__ u16 Pl[4][32 * 64];      // per-wave P, chunk ^ (row&7)
  const int bx = blockIdx.x;
  const int h = bx & 15;
  const int pj = bx >> 4;
  const int t = threadIdx.x;
  const int lane = t & 63, w = t >> 6;
  const int mh = w & 1, par = w >> 1;
  const int lrow = lane & 15, g = lane >> 4, lk = g * 8;

  // stage super-step ss (tiles 2ss, 2ss+1) of this side into buffer b
  auto STAGE = [&](int b, int ss, int nt2) {
    const int t0 = 2 * ss;
    const int t1 = (2 * ss + 1 < nt2) ? 2 * ss + 1 : nt2 - 1;
#pragma unroll
    for (int i = 0; i < 4; ++i) {
      const int rk = w * 16 + i * 4 + (lane >> 4);
      const int ck = lane & 15;
      GL2LDS(K + (size_t)(t0 * 64 + rk) * D_MODEL + h * HDIM + ((ck ^ (rk & 15)) * 8),
             Kb[b][0] + (w * 16 + i * 4) * 128);
      GL2LDS(K + (size_t)(t1 * 64 + rk) * D_MODEL + h * HDIM + ((ck ^ (rk & 15)) * 8),
             Kb[b][1] + (w * 16 + i * 4) * 128);
      const int rv = w * 32 + i * 8 + (lane >> 3);
      const int cv = lane & 7;
      GL2LDS(VT + (size_t)(h * HDIM + rv) * D_MODEL + t0 * 64 + ((cv ^ (rv & 7)) * 8),
             Vb[b][0] + (w * 32 + i * 8) * 64);
      GL2LDS(VT + (size_t)(h * HDIM + rv) * D_MODEL + t1 * 64 + ((cv ^ (rv & 7)) * 8),
             Vb[b][1] + (w * 32 + i * 8) * 64);
    }
  };

  int cur = 0;
#pragma unroll 1
  for (int side = 0; side < 2; ++side) {
    const int qt = side ? (31 - pj) : pj;
    const int nt = qt + 1;
    const int nss = (nt + 1) >> 1;
    const int qrow0 = qt * 64 + mh * 32;

    bf16x8 qf[2][4];
#pragma unroll
    for (int mi = 0; mi < 2; ++mi)
#pragma unroll
      for (int ks = 0; ks < 4; ++ks)
        qf[mi][ks] = *(const bf16x8*)(Q + (size_t)(qrow0 + mi * 16 + lrow) * D_MODEL + h * HDIM + ks * 32 + lk);

    f32x4 accO[2][8] = {};
    float m_run[2][4], l_run[2][4];
#pragma unroll
    for (int mi = 0; mi < 2; ++mi)
#pragma unroll
      for (int r = 0; r < 4; ++r) { m_run[mi][r] = -1e30f; l_run[mi][r] = 0.f; }

    STAGE(cur, 0, nt);
    __syncthreads();

#pragma unroll 1
    for (int ss = 0; ss < nss; ++ss) {
      if (ss + 1 < nss) STAGE(cur ^ 1, ss + 1, nt);   // prefetch next super-step

      const int T = 2 * ss + par;
      if (T < nt) {
        f32x4 sc[2][4] = {};
#pragma unroll
        for (int ks = 0; ks < 4; ++ks) {
          bf16x8 kf[4];
#pragma unroll
          for (int ni = 0; ni < 4; ++ni)
            kf[ni] = *(const bf16x8*)(&Kb[cur][par][(ni * 16 + lrow) * 128 + ((ks * 4 + g) ^ lrow) * 8]);
#pragma unroll
          for (int mi = 0; mi < 2; ++mi)
#pragma unroll
            for (int ni = 0; ni < 4; ++ni)
              sc[mi][ni] = __builtin_amdgcn_mfma_f32_16x16x32_bf16(qf[mi][ks], kf[ni], sc[mi][ni], 0, 0, 0);
        }

        if (T == qt) {       // diagonal tile masking only
          const int kv = T * 64;
#pragma unroll
          for (int mi = 0; mi < 2; ++mi)
#pragma unroll
            for (int ni = 0; ni < 4; ++ni) {
              const int colg = kv + ni * 16 + lrow;
#pragma unroll
              for (int r = 0; r < 4; ++r) {
                const int rowg = qrow0 + mi * 16 + g * 4 + r;
                if (colg > rowg) sc[mi][ni][r] = -1e30f;
              }
            }
        }

        // wave-parallel online softmax (exp2 domain) + defer-max (T13, THR=8)
#pragma unroll
        for (int mi = 0; mi < 2; ++mi)
#pragma unroll
          for (int r = 0; r < 4; ++r) {
            float pm = fmaxf(fmaxf(sc[mi][0][r], sc[mi][1][r]), fmaxf(sc[mi][2][r], sc[mi][3][r]));
            pm = fmaxf(pm, __shfl_xor(pm, 1));
            pm = fmaxf(pm, __shfl_xor(pm, 2));
            pm = fmaxf(pm, __shfl_xor(pm, 4));
            pm = fmaxf(pm, __shfl_xor(pm, 8));
            const float mo = m_run[mi][r];
            const bool defer = __all(pm - mo <= 8.f);   // uniform branch
            float base = mo, sf = 1.0f;
            if (!defer) {
              base = fmaxf(mo, pm);
              sf = fexp2(mo - base);
              m_run[mi][r] = base;
            }
            float rs = 0.f;
#pragma unroll
            for (int ni = 0; ni < 4; ++ni) {
              const float p = fexp2(sc[mi][ni][r] - base);
              sc[mi][ni][r] = p;
              rs += p;
            }
            rs += __shfl_xor(rs, 1);
            rs += __shfl_xor(rs, 2);
            rs += __shfl_xor(rs, 4);
            rs += __shfl_xor(rs, 8);
            l_run[mi][r] = fmaf(l_run[mi][r], sf, rs);
            if (!defer) {
#pragma unroll
              for (int dt = 0; dt < 8; ++dt) accO[mi][dt][r] *= sf;
            }
          }

        // P (C-layout) -> per-wave LDS (swizzled), read back as A-fragments
#pragma unroll
        for (int mi = 0; mi < 2; ++mi)
#pragma unroll
          for (int ni = 0; ni < 4; ++ni)
#pragma unroll
            for (int r = 0; r < 4; ++r) {
              const int row = mi * 16 + g * 4 + r;
              const int chnk = (2 * ni + (lrow >> 3)) ^ (row & 7);
              Pl[w][row * 64 + chnk * 8 + (lrow & 7)] = f2bf(sc[mi][ni][r]);
            }
        asm volatile("s_waitcnt lgkmcnt(0)" ::: "memory");

        // O += P V, swizzled reads
#pragma unroll
        for (int ks2 = 0; ks2 < 2; ++ks2) {
          bf16x8 pf[2];
#pragma unroll
          for (int mi = 0; mi < 2; ++mi) {
            const int row = mi * 16 + lrow;
            pf[mi] = *(const bf16x8*)(&Pl[w][row * 64 + ((ks2 * 4 + g) ^ (row & 7)) * 8]);
          }
#pragma unroll
          for (int dt = 0; dt < 8; ++dt) {
            const int R = dt * 16 + lrow;
            const bf16x8 vf = *(const bf16x8*)(&Vb[cur][par][R * 64 + ((ks2 * 4 + g) ^ (R & 7)) * 8]);
#pragma unroll
            for (int mi = 0; mi < 2; ++mi)
              accO[mi][dt] = __builtin_amdgcn_mfma_f32_16x16x32_bf16(pf[mi], vf, accO[mi][dt], 0, 0, 0);
          }
        }
      }
      __syncthreads();   // prefetch landed (vmcnt drain) + all reads of cur done
      cur ^= 1;
    }

    // ---- merge the two KV-parity partials via LDS (reuses Kb[0]/Vb[0] as scratch) ----
    float* mrg = (float*)&Kb[0][0][0];
    float* mlb = (float*)&Vb[0][0][0];
    if (par == 1) {
#pragma unroll
      for (int mi = 0; mi < 2; ++mi)
#pragma unroll
        for (int dt = 0; dt < 8; ++dt)
#pragma unroll
          for (int r = 0; r < 4; ++r)
            mrg[mh * 4096 + (mi * 16 + g * 4 + r) * 128 + dt * 16 + lrow] = accO[mi][dt][r];
#pragma unroll
      for (int mi = 0; mi < 2; ++mi)
#pragma unroll
        for (int r = 0; r < 4; ++r) {
          const int row = mi * 16 + g * 4 + r;
          mlb[mh * 64 + row * 2]     = m_run[mi][r];
          mlb[mh * 64 + row * 2 + 1] = l_run[mi][r];
        }
    }
    __syncthreads();
    if (par == 0) {
#pragma unroll
      for (int mi = 0; mi < 2; ++mi)
#pragma unroll
        for (int r = 0; r < 4; ++r) {
          const int row = mi * 16 + g * 4 + r;
          const float m1 = mlb[mh * 64 + row * 2];
          const float l1 = mlb[mh * 64 + row * 2 + 1];
          const float mn = fmaxf(m_run[mi][r], m1);
          const float f0 = fexp2(m_run[mi][r] - mn);
          const float f1 = fexp2(m1 - mn);
          const float inv = 1.0f / (l_run[mi][r] * f0 + l1 * f1);
          const size_t grow = (size_t)(qrow0 + row);
#pragma unroll
          for (int dt = 0; dt < 8; ++dt) {
            const float v1 = mrg[mh * 4096 + row * 128 + dt * 16 + lrow];
            O[grow * D_MODEL + h * HDIM + dt * 16 + lrow] =
                f2bf((accO[mi][dt][r] * f0 + v1 * f1) * inv);
          }
        }
    }
    __syncthreads();   // scratch free before next side's staging overwrites it
  }
}

// ---------------- launch ----------------
extern "C" void kernel_launch(void* const* d_in, const int* in_sizes, int n_in,
                              void* d_out, int out_size, void* d_ws, size_t ws_size,
                              hipStream_t stream) {
  const float* query = (const float*)d_in[0];
  const float* key_  = (const float*)d_in[1];
  const float* value = (const float*)d_in[2];
  const float* Wq    = (const float*)d_in[3];
  const float* Wk    = (const float*)d_in[4];
  const float* Wv    = (const float*)d_in[5];
  const float* Wo    = (const float*)d_in[6];
  float* out = (float*)d_out;

  const size_t TS = (size_t)SEQ * D_MODEL; // 4M elems per tensor
  u16* ws  = (u16*)d_ws;
  u16* bXq = ws + 0 * TS;
  u16* bXk = ws + 1 * TS;
  u16* bXv = ws + 2 * TS;
  u16* bWq = ws + 3 * TS;
  u16* bWk = ws + 4 * TS;
  u16* bWv = ws + 5 * TS;
  u16* bWo = ws + 6 * TS;
  u16* bQ  = ws + 7 * TS;
  u16* bK  = ws + 8 * TS;
  u16* bVT = ws + 9 * TS;
  u16* bA  = ws + 10 * TS;

  const int n4 = (int)(TS / 4);
  k_cast7<<<dim3(n4 / 256, 7), 256, 0, stream>>>(query, key_, value, Wq, Wk, Wv, Wo,
                                                 bXq, bXk, bXv, bWq, bWk, bWv, bWo);

  k_gemm_qkv<<<dim3(16, 16, 3), 256, 0, stream>>>(bXq, bXk, bXv, bWq, bWk, bWv, bQ, bK, bVT);

  k_rope<<<dim3((SEQ * NHEAD * 64) / 256, 2), 256, 0, stream>>>(bQ, bK);

  k_attn<<<dim3(256), 256, 0, stream>>>(bQ, bK, bVT, bA);

  k_gemm_out<<<dim3(32, 16), 256, 0, stream>>>(bA, bWo, out);
}

// Round 7
// 290.000 us; speedup vs baseline: 1.1827x; 1.1827x over previous
//
#include <hip/hip_runtime.h>

typedef unsigned short u16;
typedef __attribute__((ext_vector_type(8))) __bf16 bf16x8;
typedef __attribute__((ext_vector_type(4))) float f32x4;

#define D_MODEL 2048
#define SEQ 2048
#define NHEAD 16
#define HDIM 128

#define AS1 __attribute__((address_space(1)))
#define AS3 __attribute__((address_space(3)))
#define GL2LDS(g, l) __builtin_amdgcn_global_load_lds((AS1 const void*)(g), (AS3 void*)(l), 16, 0, 0)

__device__ __forceinline__ u16 f2bf(float f) {
  unsigned u = __float_as_uint(f);
  u += 0x7fff + ((u >> 16) & 1);   // RNE
  return (u16)(u >> 16);
}
__device__ __forceinline__ float bf2f(u16 h) {
  return __uint_as_float(((unsigned)h) << 16);
}
__device__ __forceinline__ float fexp2(float x) {
#if __has_builtin(__builtin_amdgcn_exp2f)
  return __builtin_amdgcn_exp2f(x);
#else
  return __expf(x * 0.69314718055994531f);
#endif
}

// ---------------- fused fp32 -> bf16 casts (7 tensors, one launch) ----------------
__global__ __launch_bounds__(256) void k_cast7(const float* i0, const float* i1, const float* i2,
                                               const float* i3, const float* i4, const float* i5,
                                               const float* i6,
                                               u16* o0, u16* o1, u16* o2, u16* o3, u16* o4,
                                               u16* o5, u16* o6) {
  const float* in; u16* out;
  switch (blockIdx.y) {
    case 0: in = i0; out = o0; break;
    case 1: in = i1; out = o1; break;
    case 2: in = i2; out = o2; break;
    case 3: in = i3; out = o3; break;
    case 4: in = i4; out = o4; break;
    case 5: in = i5; out = o5; break;
    default: in = i6; out = o6; break;
  }
  const int i = blockIdx.x * blockDim.x + threadIdx.x;
  const float4 v = reinterpret_cast<const float4*>(in)[i];
  ushort4 o;
  o.x = f2bf(v.x); o.y = f2bf(v.y); o.z = f2bf(v.z); o.w = f2bf(v.w);
  reinterpret_cast<ushort4*>(out)[i] = o;
}

// ---------------- GEMM staging: 128x64 tile, rows of 8 chunks, chunk ^= (row&7) swizzle ----------------
__device__ __forceinline__ void stage128(const u16* __restrict__ P, u16* dst, int row0, int kt,
                                         int t, int w) {
#pragma unroll
  for (int c = 0; c < 4; ++c) {
    const int r = (c * 2048 + t * 8) >> 6;            // tile row 0..127
    const int ch = ((t & 7) ^ (r & 7)) * 8;           // swizzled k-chunk
    GL2LDS(P + (size_t)(row0 + r) * D_MODEL + kt + ch, dst + c * 2048 + w * 512);
  }
}
__device__ __forceinline__ void stage64(const u16* __restrict__ P, u16* dst, int row0, int kt,
                                        int t, int w) {
#pragma unroll
  for (int c = 0; c < 2; ++c) {
    const int r = (c * 2048 + t * 8) >> 6;            // tile row 0..63
    const int ch = ((t & 7) ^ (r & 7)) * 8;
    GL2LDS(P + (size_t)(row0 + r) * D_MODEL + kt + ch, dst + c * 2048 + w * 512);
  }
}

// ---------------- NT GEMM: C[m,n] = sum_k A[m,k]*B[n,k], 128x128 tile, dbuf prefetch ----------------
__device__ __forceinline__ void gemm_nt_body(const u16* __restrict__ A, const u16* __restrict__ B,
                                             void* __restrict__ C, u16* As0, u16* As1,
                                             u16* Bs0, u16* Bs1, int outmode) {
  const int tn = blockIdx.x, tm = blockIdx.y;
  const int t = threadIdx.x;
  const int lane = t & 63, w = t >> 6;
  const int wr = w >> 1, wc = w & 1;
  const int lrow = lane & 15, g = lane >> 4;
  f32x4 acc[4][4] = {};

  stage128(A, As0, tm * 128, 0, t, w);
  stage128(B, Bs0, tn * 128, 0, t, w);
  __syncthreads();

  u16 *Ar = As0, *Br = Bs0, *Aw = As1, *Bw = Bs1;
#pragma unroll 1
  for (int kt = 0; kt < D_MODEL; kt += 64) {
    if (kt + 64 < D_MODEL) {           // issue next-tile loads BEFORE compute
      stage128(A, Aw, tm * 128, kt + 64, t, w);
      stage128(B, Bw, tn * 128, kt + 64, t, w);
    }
#pragma unroll
    for (int kk = 0; kk < 2; ++kk) {
      bf16x8 af[4], bfr[4];
#pragma unroll
      for (int i = 0; i < 4; ++i) {
        const int sw = (((kk << 2) + g) ^ (lrow & 7)) * 8;
        af[i]  = *(const bf16x8*)(Ar + (wr * 64 + i * 16 + lrow) * 64 + sw);
        bfr[i] = *(const bf16x8*)(Br + (wc * 64 + i * 16 + lrow) * 64 + sw);
      }
#pragma unroll
      for (int i = 0; i < 4; ++i)
#pragma unroll
        for (int j = 0; j < 4; ++j)
          acc[i][j] = __builtin_amdgcn_mfma_f32_16x16x32_bf16(af[i], bfr[j], acc[i][j], 0, 0, 0);
    }
    __syncthreads();
    u16* tp;
    tp = Ar; Ar = Aw; Aw = tp;
    tp = Br; Br = Bw; Bw = tp;
  }

  // C layout (measured m89): col = lane&15, row = (lane>>4)*4 + reg
  const int crow0 = tm * 128 + wr * 64 + (lane >> 4) * 4;
  const int ccol0 = tn * 128 + wc * 64 + lrow;
  if (outmode == 2) {
#pragma unroll
    for (int i = 0; i < 4; ++i)
#pragma unroll
      for (int j = 0; j < 4; ++j) {
        ushort4 o;
        o.x = f2bf(acc[i][j][0]); o.y = f2bf(acc[i][j][1]);
        o.z = f2bf(acc[i][j][2]); o.w = f2bf(acc[i][j][3]);
        *(ushort4*)((u16*)C + (size_t)(ccol0 + j * 16) * D_MODEL + crow0 + i * 16) = o;
      }
  } else {
#pragma unroll
    for (int i = 0; i < 4; ++i)
#pragma unroll
      for (int j = 0; j < 4; ++j)
#pragma unroll
        for (int r = 0; r < 4; ++r)
          ((u16*)C)[(size_t)(crow0 + i * 16 + r) * D_MODEL + ccol0 + j * 16] = f2bf(acc[i][j][r]);
  }
}

__global__ __launch_bounds__(256, 2) void k_gemm_qkv(const u16* Xq, const u16* Xk, const u16* Xv,
                                                     const u16* Wq, const u16* Wk, const u16* Wv,
                                                     u16* Q, u16* K, u16* VT) {
  __shared__ u16 As[2][128 * 64], Bs[2][128 * 64];
  const int z = blockIdx.z;
  const u16* A = (z == 0) ? Xq : (z == 1) ? Xk : Xv;
  const u16* B = (z == 0) ? Wq : (z == 1) ? Wk : Wv;
  u16* C = (z == 0) ? Q : (z == 1) ? K : VT;
  gemm_nt_body(A, B, C, As[0], As[1], Bs[0], Bs[1], (z == 2) ? 2 : 0);
}

// ---------------- out-proj GEMM: 128x64 tiles -> 512 blocks, dbuf prefetch ----------------
__global__ __launch_bounds__(256, 2) void k_gemm_out(const u16* __restrict__ A, const u16* __restrict__ B,
                                                     float* __restrict__ C) {
  __shared__ u16 As[2][128 * 64], Bs[2][64 * 64];
  const int tn = blockIdx.x, tm = blockIdx.y;
  const int t = threadIdx.x;
  const int lane = t & 63, w = t >> 6;
  const int wr = w >> 1, wc = w & 1;
  const int lrow = lane & 15, g = lane >> 4;
  f32x4 acc[4][2] = {};

  stage128(A, As[0], tm * 128, 0, t, w);
  stage64(B, Bs[0], tn * 64, 0, t, w);
  __syncthreads();

  u16 *Ar = As[0], *Br = Bs[0], *Aw = As[1], *Bw = Bs[1];
#pragma unroll 1
  for (int kt = 0; kt < D_MODEL; kt += 64) {
    if (kt + 64 < D_MODEL) {
      stage128(A, Aw, tm * 128, kt + 64, t, w);
      stage64(B, Bw, tn * 64, kt + 64, t, w);
    }
#pragma unroll
    for (int kk = 0; kk < 2; ++kk) {
      bf16x8 af[4], bfr[2];
#pragma unroll
      for (int i = 0; i < 4; ++i) {
        const int sw = (((kk << 2) + g) ^ (lrow & 7)) * 8;
        af[i] = *(const bf16x8*)(Ar + (wr * 64 + i * 16 + lrow) * 64 + sw);
        if (i < 2) bfr[i] = *(const bf16x8*)(Br + (wc * 32 + i * 16 + lrow) * 64 + sw);
      }
#pragma unroll
      for (int i = 0; i < 4; ++i)
#pragma unroll
        for (int j = 0; j < 2; ++j)
          acc[i][j] = __builtin_amdgcn_mfma_f32_16x16x32_bf16(af[i], bfr[j], acc[i][j], 0, 0, 0);
    }
    __syncthreads();
    u16* tp;
    tp = Ar; Ar = Aw; Aw = tp;
    tp = Br; Br = Bw; Bw = tp;
  }
  const int crow0 = tm * 128 + wr * 64 + (lane >> 4) * 4;
  const int ccol0 = tn * 64 + wc * 32 + lrow;
#pragma unroll
  for (int i = 0; i < 4; ++i)
#pragma unroll
    for (int j = 0; j < 2; ++j)
#pragma unroll
      for (int r = 0; r < 4; ++r)
        C[(size_t)(crow0 + i * 16 + r) * D_MODEL + ccol0 + j * 16] = acc[i][j][r];
}

// ---------------- RoPE (rotate_half); Q gets log2(e)/sqrt(hd) for exp2-domain softmax ----------------
__global__ __launch_bounds__(256) void k_rope(u16* Q, u16* K) {
  const int idx = blockIdx.x * blockDim.x + threadIdx.x; // 0 .. SEQ*NHEAD*64-1
  u16* X = blockIdx.y ? K : Q;
  const float scale = blockIdx.y ? 1.0f : (1.4426950408889634f * 0.08838834764831845f);
  const int s = idx >> 10;
  const int h = (idx >> 6) & 15;
  const int j = idx & 63;
  const float freq = __expf((float)j * -0.14391156831212787f); // -ln(10000)/64
  float sn, cs;
  sincosf((float)s * freq, &sn, &cs);
  const size_t base = (size_t)s * D_MODEL + h * HDIM + j;
  const float x1 = bf2f(X[base]), x2 = bf2f(X[base + 64]);
  X[base]      = f2bf((x1 * cs - x2 * sn) * scale);
  X[base + 64] = f2bf((x2 * cs + x1 * sn) * scale);
}

// ---------------- causal flash attention: 8-wave blocks, concurrent paired q-tiles, swapped QK^T ----------
// 256 blocks x 512 thr. Block (h = bx&15, pj = bx>>4) computes q-tiles {pj, 31-pj} CONCURRENTLY:
// waves 0-3 = side A (qt=pj), waves 4-7 = side B (qt=31-pj); within a side: (par, mh).
// One shared K/V staging stream (tiles 0..31-pj) feeds both sides. 2 waves/SIMD.
// Swapped MFMAs: S^T = mfma(K,Q) puts q in lane&15 -> softmax is lane-local (2 shfl_xor only);
// O^T = mfma(V,P) keeps q in lane&15 -> rescale/epilogue lane-local.
// LDS: Kb 32K + Vb 32K + Pl 32K = 96 KB.
__global__ __launch_bounds__(512) void k_attn(const u16* __restrict__ Q, const u16* __restrict__ K,
                                              const u16* __restrict__ VT, u16* __restrict__ O) {
  __shared__ u16 Kb[2][64 * 128];   // [tile parity][row][chunk pos ^ (row&15)]
  __shared__ u16 Vb[2][128 * 64];   // [tile parity][d-row][chunk pos ^ (row&7)]
  __shared__ u16 Pl[8][32 * 64];    // per-wave P: [q_local][kv, 16B-chunk pos ^ (q_local&7)]
  const int bx = blockIdx.x;
  const int h = bx & 15;
  const int pj = bx >> 4;
  const int t = threadIdx.x;
  const int lane = t & 63, w = t >> 6;
  const int side = w >> 2;
  const int par = (w >> 1) & 1;
  const int mh = w & 1;
  const int lrow = lane & 15, g = lane >> 4, lk = g * 8;
  const int qt = side ? (31 - pj) : pj;
  const int nt = qt + 1;
  const int qrow0 = qt * 64 + mh * 32;
  const int ntB = 32 - pj;                 // tiles needed by the long side
  const int nss = (ntB + 1) >> 1;

  // Q fragments (pre-scaled by log2e/sqrt(128) in k_rope)
  bf16x8 qf[2][4];
#pragma unroll
  for (int mi = 0; mi < 2; ++mi)
#pragma unroll
    for (int ks = 0; ks < 4; ++ks)
      qf[mi][ks] = *(const bf16x8*)(Q + (size_t)(qrow0 + mi * 16 + lrow) * D_MODEL + h * HDIM + ks * 32 + lk);

  f32x4 accO[2][8] = {};                   // [mi][dt]: row=d (g*4+reg), col=q (lane&15)
  float m_run[2] = {-1e30f, -1e30f};       // per-lane: q-row = qrow0 + mi*16 + lrow
  float l_run[2] = {0.f, 0.f};

#pragma unroll 1
  for (int ss = 0; ss < nss; ++ss) {
    const int t0 = 2 * ss;
    const int t1 = (2 * ss + 1 < ntB) ? 2 * ss + 1 : ntB - 1;
    // ---- cooperative stage: 2 K-tiles + 2 V-tiles, all 512 threads, pre-swizzled source ----
#pragma unroll
    for (int i = 0; i < 4; ++i) {
      {
        const int idx = i * 512 + t;                     // 0..2047: [tile][row 0..63][ck 0..15]
        const int tl = idx >> 10, row = (idx >> 4) & 63, ck = idx & 15;
        GL2LDS(K + (size_t)((tl ? t1 : t0) * 64 + row) * D_MODEL + h * HDIM + ((ck ^ (row & 15)) * 8),
               Kb[0] + idx * 8);
      }
      {
        const int idx = i * 512 + t;                     // [tile][d-row 0..127][cv 0..7]
        const int tl = idx >> 10, row = (idx >> 3) & 127, cv = idx & 7;
        GL2LDS(VT + (size_t)(h * HDIM + row) * D_MODEL + (tl ? t1 : t0) * 64 + ((cv ^ (row & 7)) * 8),
               Vb[0] + idx * 8);
      }
    }
    __syncthreads();

    const int T = 2 * ss + par;          // tile T lives in buffer [par]
    if (T < nt) {
      // ---- S^T = K Q^T : scs[kb][mi], lane holds q=lane&15, kv = kb*16 + g*4 + reg ----
      f32x4 scs[4][2] = {};
#pragma unroll
      for (int ks = 0; ks < 4; ++ks) {
        bf16x8 kf[4];
#pragma unroll
        for (int kb = 0; kb < 4; ++kb)
          kf[kb] = *(const bf16x8*)(&Kb[par][(kb * 16 + lrow) * 128 + ((ks * 4 + g) ^ lrow) * 8]);
#pragma unroll
        for (int kb = 0; kb < 4; ++kb)
#pragma unroll
          for (int mi = 0; mi < 2; ++mi)
            scs[kb][mi] = __builtin_amdgcn_mfma_f32_16x16x32_bf16(kf[kb], qf[mi][ks], scs[kb][mi], 0, 0, 0);
      }

      if (T == qt) {       // diagonal tile masking only
#pragma unroll
        for (int kb = 0; kb < 4; ++kb)
#pragma unroll
          for (int mi = 0; mi < 2; ++mi) {
            const int qg = qrow0 + mi * 16 + lrow;
#pragma unroll
            for (int r = 0; r < 4; ++r) {
              const int kvg = T * 64 + kb * 16 + g * 4 + r;
              if (kvg > qg) scs[kb][mi][r] = -1e30f;
            }
          }
      }

      // ---- lane-local online softmax (exp2 domain) + defer-max (THR=8) ----
#pragma unroll
      for (int mi = 0; mi < 2; ++mi) {
        float pm = -1e30f;
#pragma unroll
        for (int kb = 0; kb < 4; ++kb)
#pragma unroll
          for (int r = 0; r < 4; ++r) pm = fmaxf(pm, scs[kb][mi][r]);
        pm = fmaxf(pm, __shfl_xor(pm, 16));
        pm = fmaxf(pm, __shfl_xor(pm, 32));
        const float mo = m_run[mi];
        const bool defer = __all(pm - mo <= 8.f);
        float base = mo, sf = 1.0f;
        if (!defer) {
          base = fmaxf(mo, pm);
          sf = fexp2(mo - base);
          m_run[mi] = base;
        }
        float rs = 0.f;
#pragma unroll
        for (int kb = 0; kb < 4; ++kb)
#pragma unroll
          for (int r = 0; r < 4; ++r) {
            const float p = fexp2(scs[kb][mi][r] - base);
            scs[kb][mi][r] = p;
            rs += p;
          }
        rs += __shfl_xor(rs, 16);
        rs += __shfl_xor(rs, 32);
        l_run[mi] = fmaf(l_run[mi], sf, rs);
        if (!defer) {
#pragma unroll
          for (int dt = 0; dt < 8; ++dt)
#pragma unroll
            for (int r = 0; r < 4; ++r) accO[mi][dt][r] *= sf;
        }
      }

      // ---- P -> per-wave LDS: kv-consecutive regs pack to ds_write_b64 ----
#pragma unroll
      for (int mi = 0; mi < 2; ++mi) {
        const int row = mi * 16 + lrow;
#pragma unroll
        for (int kb = 0; kb < 4; ++kb) {
          ushort4 o;
          o.x = f2bf(scs[kb][mi][0]); o.y = f2bf(scs[kb][mi][1]);
          o.z = f2bf(scs[kb][mi][2]); o.w = f2bf(scs[kb][mi][3]);
          *(ushort4*)(&Pl[w][row * 64 + (((kb << 1) + (g >> 1)) ^ (row & 7)) * 8 + (g & 1) * 4]) = o;
        }
      }
      asm volatile("s_waitcnt lgkmcnt(0)" ::: "memory");
      __builtin_amdgcn_sched_barrier(0);

      // ---- O^T += V P : accO[mi][dt] = mfma(vf, pf) ----
#pragma unroll
      for (int ks2 = 0; ks2 < 2; ++ks2) {
        bf16x8 pf[2];
#pragma unroll
        for (int mi = 0; mi < 2; ++mi) {
          const int row = mi * 16 + lrow;
          pf[mi] = *(const bf16x8*)(&Pl[w][row * 64 + ((ks2 * 4 + g) ^ (row & 7)) * 8]);
        }
#pragma unroll
        for (int dt = 0; dt < 8; ++dt) {
          const int R = dt * 16 + lrow;
          const bf16x8 vf = *(const bf16x8*)(&Vb[par][R * 64 + ((ks2 * 4 + g) ^ (R & 7)) * 8]);
#pragma unroll
          for (int mi = 0; mi < 2; ++mi)
            accO[mi][dt] = __builtin_amdgcn_mfma_f32_16x16x32_bf16(vf, pf[mi], accO[mi][dt], 0, 0, 0);
        }
      }
    }
    __syncthreads();
  }

  // ---- merge KV-parity partials per side (lane-local m/l) ----
  float* mrg = side ? (float*)&Vb[0][0] : (float*)&Kb[0][0];   // 2 mh x 32 q x 128 d = 32 KB
  float* mlb = (float*)&Pl[0][0] + side * 128;
  if (par == 1) {
#pragma unroll
    for (int mi = 0; mi < 2; ++mi) {
      const int ql = mi * 16 + lrow;
#pragma unroll
      for (int dt = 0; dt < 8; ++dt)
        *(f32x4*)(&mrg[mh * 4096 + ql * 128 + dt * 16 + g * 4]) = accO[mi][dt];
      if (g == 0) {
        mlb[mh * 64 + ql * 2]     = m_run[mi];
        mlb[mh * 64 + ql * 2 + 1] = l_run[mi];
      }
    }
  }
  __syncthreads();
  if (par == 0) {
#pragma unroll
    for (int mi = 0; mi < 2; ++mi) {
      const int ql = mi * 16 + lrow;
      const float m1 = mlb[mh * 64 + ql * 2];
      const float l1 = mlb[mh * 64 + ql * 2 + 1];
      const float mn = fmaxf(m_run[mi], m1);
      const float f0 = fexp2(m_run[mi] - mn);
      const float f1 = fexp2(m1 - mn);
      const float inv = 1.0f / (l_run[mi] * f0 + l1 * f1);
      const size_t grow = (size_t)(qrow0 + ql);
#pragma unroll
      for (int dt = 0; dt < 8; ++dt) {
        const f32x4 v1 = *(const f32x4*)(&mrg[mh * 4096 + ql * 128 + dt * 16 + g * 4]);
        ushort4 o;
        o.x = f2bf((accO[mi][dt][0] * f0 + v1[0] * f1) * inv);
        o.y = f2bf((accO[mi][dt][1] * f0 + v1[1] * f1) * inv);
        o.z = f2bf((accO[mi][dt][2] * f0 + v1[2] * f1) * inv);
        o.w = f2bf((accO[mi][dt][3] * f0 + v1[3] * f1) * inv);
        *(ushort4*)(&O[grow * D_MODEL + h * HDIM + dt * 16 + g * 4]) = o;
      }
    }
  }
}

// ---------------- launch ----------------
extern "C" void kernel_launch(void* const* d_in, const int* in_sizes, int n_in,
                              void* d_out, int out_size, void* d_ws, size_t ws_size,
                              hipStream_t stream) {
  const float* query = (const float*)d_in[0];
  const float* key_  = (const float*)d_in[1];
  const float* value = (const float*)d_in[2];
  const float* Wq    = (const float*)d_in[3];
  const float* Wk    = (const float*)d_in[4];
  const float* Wv    = (const float*)d_in[5];
  const float* Wo    = (const float*)d_in[6];
  float* out = (float*)d_out;

  const size_t TS = (size_t)SEQ * D_MODEL; // 4M elems per tensor
  u16* ws  = (u16*)d_ws;
  u16* bXq = ws + 0 * TS;
  u16* bXk = ws + 1 * TS;
  u16* bXv = ws + 2 * TS;
  u16* bWq = ws + 3 * TS;
  u16* bWk = ws + 4 * TS;
  u16* bWv = ws + 5 * TS;
  u16* bWo = ws + 6 * TS;
  u16* bQ  = ws + 7 * TS;
  u16* bK  = ws + 8 * TS;
  u16* bVT = ws + 9 * TS;
  u16* bA  = ws + 10 * TS;

  const int n4 = (int)(TS / 4);
  k_cast7<<<dim3(n4 / 256, 7), 256, 0, stream>>>(query, key_, value, Wq, Wk, Wv, Wo,
                                                 bXq, bXk, bXv, bWq, bWk, bWv, bWo);

  k_gemm_qkv<<<dim3(16, 16, 3), 256, 0, stream>>>(bXq, bXk, bXv, bWq, bWk, bWv, bQ, bK, bVT);

  k_rope<<<dim3((SEQ * NHEAD * 64) / 256, 2), 256, 0, stream>>>(bQ, bK);

  k_attn<<<dim3(256), 512, 0, stream>>>(bQ, bK, bVT, bA);

  k_gemm_out<<<dim3(32, 16), 256, 0, stream>>>(bA, bWo, out);
}